// Round 14
// baseline (179.674 us; speedup 1.0000x reference)
//
#include <hip/hip_runtime.h>

typedef float f4 __attribute__((ext_vector_type(4)));
typedef float f32x4 __attribute__((ext_vector_type(4)));
typedef short bf16x8 __attribute__((ext_vector_type(8)));
typedef unsigned short u16x8 __attribute__((ext_vector_type(8)));

static __device__ __forceinline__ unsigned short f2bf(float f) {
    unsigned int x = __builtin_bit_cast(unsigned int, f);
    x = (x + 0x7fffu + ((x >> 16) & 1u)) >> 16;
    return (unsigned short)x;
}
static __device__ __forceinline__ float bf2f(unsigned short h) {
    unsigned int x = ((unsigned int)h) << 16;
    return __builtin_bit_cast(float, x);
}

static __device__ __forceinline__ void gll16(const unsigned short* g, unsigned short* l) {
    __builtin_amdgcn_global_load_lds(
        (__attribute__((address_space(1))) void*)(g),
        (__attribute__((address_space(3))) void*)(l), 16, 0, 0);
}

// LDS frag offset (shorts) for row r, true 16B-slot s (involution, both sides)
static __device__ __forceinline__ int fragoff(int r, int s) {
    return r * 32 + ((s ^ ((r >> 1) & 3)) << 3);
}

// ================= stage 1: merged {e,p} GEMM, A split hi+lo, W hi-only,
//                   in-staging f32->bf16 conversion + W_out cvt blocks
struct GJobF {
    const float *A, *W;
    int lda, ldw;
    const float* bias;
    unsigned short *Ch, *Cl;
    int N, K, nbx;
};

__global__ __launch_bounds__(256, 3) void gemmcvt64(
    GJobF j0, GJobF j1, int nblk0, int nblk1,
    const float* __restrict__ Wo, unsigned short* __restrict__ Wo_h, int nWo8)
{
    __shared__ unsigned short lds[2][3][64 * 32];   // 2 bufs x {Ah,Al,Wh}

    const int bid = blockIdx.x;
    const int tid = threadIdx.x;

    if (bid >= nblk0 + nblk1) {
        const int nblkc = (int)gridDim.x - nblk0 - nblk1;
        for (int g = (bid - nblk0 - nblk1) * 256 + tid; g < nWo8; g += nblkc * 256) {
            const int idx = g * 8;
            f4 a = *(const f4*)(Wo + idx);
            f4 b = *(const f4*)(Wo + idx + 4);
            u16x8 hv;
            float s[8] = { a.x, a.y, a.z, a.w, b.x, b.y, b.z, b.w };
            #pragma unroll
            for (int i = 0; i < 8; ++i) hv[i] = f2bf(s[i]);
            *(u16x8*)(Wo_h + idx) = hv;
        }
        return;
    }

    const bool first = bid < nblk0;
    const GJobF J = first ? j0 : j1;
    const int local = first ? bid : bid - nblk0;
    const int m0 = (local % J.nbx) * 64;
    const int n0 = (local / J.nbx) * 64;

    const int lane = tid & 63;
    const int wid  = tid >> 6;
    const int wr   = wid >> 1, wc = wid & 1;
    const int lrow = lane & 15;
    const int s    = lane >> 4;

    const int row  = tid >> 2, slot = tid & 3;
    const int woff = fragoff(row, slot);
    const float* pA = J.A + (size_t)(m0 + row) * J.lda + slot * 8;
    const float* pW = J.W + (size_t)(n0 + row) * J.ldw + slot * 8;

    f4 ra0, ra1, rw0, rw1;

#define LOADREGS(k0) do { \
    ra0 = *(const f4*)(pA + (k0));     ra1 = *(const f4*)(pA + (k0) + 4); \
    rw0 = *(const f4*)(pW + (k0));     rw1 = *(const f4*)(pW + (k0) + 4); \
} while (0)

#define CVTWRITE(buf) do { \
    u16x8 ha, la, hw; \
    float sa[8] = { ra0.x, ra0.y, ra0.z, ra0.w, ra1.x, ra1.y, ra1.z, ra1.w }; \
    float sw[8] = { rw0.x, rw0.y, rw0.z, rw0.w, rw1.x, rw1.y, rw1.z, rw1.w }; \
    _Pragma("unroll") \
    for (int i = 0; i < 8; ++i) { \
        unsigned short h = f2bf(sa[i]); \
        ha[i] = h; la[i] = f2bf(sa[i] - bf2f(h)); \
        hw[i] = f2bf(sw[i]); \
    } \
    *(u16x8*)&lds[buf][0][woff] = ha; \
    *(u16x8*)&lds[buf][1][woff] = la; \
    *(u16x8*)&lds[buf][2][woff] = hw; \
} while (0)

    f32x4 acc[2][2];
    #pragma unroll
    for (int i = 0; i < 2; ++i)
        #pragma unroll
        for (int j = 0; j < 2; ++j) acc[i][j] = (f32x4){0.f, 0.f, 0.f, 0.f};

    const int nt = J.K / 32;

    LOADREGS(0);
    CVTWRITE(0);
    __syncthreads();

    int cur = 0;
    for (int t = 0; t < nt; ++t) {
        if (t + 1 < nt) LOADREGS((t + 1) * 32);

        bf16x8 ah[2], al[2], wh[2];
        #pragma unroll
        for (int i = 0; i < 2; ++i) {
            const int ra = wr * 32 + i * 16 + lrow;
            const int rw = wc * 32 + i * 16 + lrow;
            ah[i] = *(const bf16x8*)&lds[cur][0][fragoff(ra, s)];
            al[i] = *(const bf16x8*)&lds[cur][1][fragoff(ra, s)];
            wh[i] = *(const bf16x8*)&lds[cur][2][fragoff(rw, s)];
        }
        #pragma unroll
        for (int i = 0; i < 2; ++i)
            #pragma unroll
            for (int j = 0; j < 2; ++j) {
                acc[i][j] = __builtin_amdgcn_mfma_f32_16x16x32_bf16(ah[i], wh[j], acc[i][j], 0, 0, 0);
                acc[i][j] = __builtin_amdgcn_mfma_f32_16x16x32_bf16(al[i], wh[j], acc[i][j], 0, 0, 0);
            }

        if (t + 1 < nt) {
            CVTWRITE(cur ^ 1);
            __syncthreads();
            cur ^= 1;
        }
    }
#undef LOADREGS
#undef CVTWRITE

    #pragma unroll
    for (int i = 0; i < 2; ++i) {
        const int rbase = m0 + wr * 32 + i * 16 + (lane >> 4) * 4;
        #pragma unroll
        for (int j = 0; j < 2; ++j) {
            const int col = n0 + wc * 32 + j * 16 + (lane & 15);
            const float bv = J.bias[col];
            #pragma unroll
            for (int r = 0; r < 4; ++r) {
                float v = acc[i][j][r] + bv;
                size_t off = (size_t)(rbase + r) * J.N + col;
                unsigned short h = f2bf(v);
                J.Ch[off] = h;
                J.Cl[off] = f2bf(v - bf2f(h));
            }
        }
    }
}

// ================= fused stage 2 + bcast =================

// stage-2 tile body: A hi+lo planes, W hi, 64M x 128N, 2-buf DMA pipeline
static __device__ __forceinline__ void gemm_tile_64x128(
    unsigned short* lds,   // [2][4][2048] shorts
    const unsigned short* __restrict__ Ah, const unsigned short* __restrict__ Al,
    const unsigned short* __restrict__ Wh, int lda, int ldw, int K,
    const float* __restrict__ bias, float* __restrict__ Cf, int N,
    int m0, int n0, int tid)
{
    const int lane = tid & 63;
    const int wid  = tid >> 6;
    const int wr   = wid >> 1, wc = wid & 1;
    const int lrow = lane & 15;
    const int s    = lane >> 4;

    const int arow  = wid * 16 + (lane >> 2);
    const int aslot = (lane & 3) ^ ((arow >> 1) & 3);
    const size_t gA = (size_t)(m0 + arow) * lda + aslot * 8;
    const int wrow0 = wid * 32 + (lane >> 2);
    const int wrow1 = wrow0 + 16;
    const int wsl0  = (lane & 3) ^ ((wrow0 >> 1) & 3);
    const int wsl1  = (lane & 3) ^ ((wrow1 >> 1) & 3);
    const size_t gW0 = (size_t)(n0 + wrow0) * ldw + wsl0 * 8;
    const size_t gW1 = (size_t)(n0 + wrow1) * ldw + wsl1 * 8;

#define STAGE(buf, k0) do { \
    gll16(Ah + gA + (k0),  &lds[((buf) * 4 + 0) * 2048 + wid * 512]); \
    gll16(Al + gA + (k0),  &lds[((buf) * 4 + 1) * 2048 + wid * 512]); \
    gll16(Wh + gW0 + (k0), &lds[((buf) * 4 + 2 + (wid >> 1)) * 2048 + (wid & 1) * 1024]); \
    gll16(Wh + gW1 + (k0), &lds[((buf) * 4 + 2 + (wid >> 1)) * 2048 + (wid & 1) * 1024 + 512]); \
} while (0)

    f32x4 acc[2][4];
    #pragma unroll
    for (int i = 0; i < 2; ++i)
        #pragma unroll
        for (int j = 0; j < 4; ++j) acc[i][j] = (f32x4){0.f, 0.f, 0.f, 0.f};

    const int nt = K / 32;

    STAGE(0, 0);
    asm volatile("s_waitcnt vmcnt(0)" ::: "memory");
    __syncthreads();

    int cur = 0;
    for (int t = 0; t < nt; ++t) {
        if (t + 1 < nt) STAGE(cur ^ 1, (t + 1) * 32);

        bf16x8 ah[2], al[2], wh[4];
        #pragma unroll
        for (int i = 0; i < 2; ++i) {
            const int ra = wr * 32 + i * 16 + lrow;
            ah[i] = *(const bf16x8*)&lds[(cur * 4 + 0) * 2048 + fragoff(ra, s)];
            al[i] = *(const bf16x8*)&lds[(cur * 4 + 1) * 2048 + fragoff(ra, s)];
        }
        #pragma unroll
        for (int j = 0; j < 4; ++j) {
            const int rw = wc * 64 + j * 16 + lrow;
            wh[j] = *(const bf16x8*)&lds[(cur * 4 + 2 + (rw >> 6)) * 2048 + fragoff(rw & 63, s)];
        }
        #pragma unroll
        for (int i = 0; i < 2; ++i)
            #pragma unroll
            for (int j = 0; j < 4; ++j) {
                acc[i][j] = __builtin_amdgcn_mfma_f32_16x16x32_bf16(ah[i], wh[j], acc[i][j], 0, 0, 0);
                acc[i][j] = __builtin_amdgcn_mfma_f32_16x16x32_bf16(al[i], wh[j], acc[i][j], 0, 0, 0);
            }

        if (t + 1 < nt) {
            asm volatile("s_waitcnt vmcnt(0)" ::: "memory");
            __syncthreads();
            cur ^= 1;
        }
    }
#undef STAGE

    #pragma unroll
    for (int i = 0; i < 2; ++i) {
        const int rbase = m0 + wr * 32 + i * 16 + (lane >> 4) * 4;
        #pragma unroll
        for (int j = 0; j < 4; ++j) {
            const int col = n0 + wc * 64 + j * 16 + (lane & 15);
            const float bv = bias ? bias[col] : 0.f;
            #pragma unroll
            for (int r = 0; r < 4; ++r)
                Cf[(size_t)(rbase + r) * N + col] = acc[i][j][r] + bv;
        }
    }
    __syncthreads();   // LDS reusable for next job
}

__global__ __launch_bounds__(128) void zero_flags(int* flags, int n) {
    if ((int)threadIdx.x < n) flags[threadIdx.x] = 0;
}

// fused: blocks 0..NG-1 = persistent GEMM workers (queue: 64 Y then 256 X,
// m-major -> X panels complete progressively); blocks NG.. = bcast waiters.
#define NG 192
__global__ __launch_bounds__(256, 4) void fused2(
    const unsigned short* __restrict__ e_h, const unsigned short* __restrict__ e_l,
    const unsigned short* __restrict__ p_h, const unsigned short* __restrict__ p_l,
    const unsigned short* __restrict__ Wo_h,
    const float* __restrict__ b_out,
    float* ws_X, float* ws_Y, float* __restrict__ out, int* flags)
{
    __shared__ unsigned short lds[2 * 4 * 2048];   // 32 KB
    __shared__ int s_job;
    const int tid = threadIdx.x;

    int* job_ctr = flags + 0;
    int* y_f = flags + 1;          // target 64
    int* x_f = flags + 2;          // [32], target 8 each

    if ((int)blockIdx.x < NG) {
        for (;;) {
            __syncthreads();
            if (tid == 0) s_job = atomicAdd(job_ctr, 1);
            __syncthreads();
            const int j = s_job;
            if (j >= 320) return;
            if (j < 64) {          // Y tile: 8m x 8n grid of 64x128
                const int m = j >> 3, n = j & 7;
                gemm_tile_64x128(lds, p_h, p_l, Wo_h + 512, 512, 1024, 512,
                                 nullptr, ws_Y, 1024, m * 64, n * 128, tid);
                __syncthreads();
                if (tid == 0)
                    __hip_atomic_fetch_add(y_f, 1, __ATOMIC_RELEASE, __HIP_MEMORY_SCOPE_AGENT);
            } else {               // X tile: 32m x 8n, m-major
                const int jl = j - 64, m = jl >> 3, n = jl & 7;
                gemm_tile_64x128(lds, e_h, e_l, Wo_h, 512, 1024, 512,
                                 b_out, ws_X, 1024, m * 64, n * 128, tid);
                __syncthreads();
                if (tid == 0)
                    __hip_atomic_fetch_add(&x_f[m], 1, __ATOMIC_RELEASE, __HIP_MEMORY_SCOPE_AGENT);
            }
        }
    }

    // ---- bcast waiter: 4 bt-rows per block
    const int bt0 = ((int)blockIdx.x - NG) * 4;
    if (tid == 0) {
        while (__hip_atomic_load(y_f, __ATOMIC_RELAXED, __HIP_MEMORY_SCOPE_AGENT) < 64)
            __builtin_amdgcn_s_sleep(8);
        while (__hip_atomic_load(&x_f[bt0 >> 6], __ATOMIC_RELAXED, __HIP_MEMORY_SCOPE_AGENT) < 8)
            __builtin_amdgcn_s_sleep(8);
        (void)__hip_atomic_load(y_f, __ATOMIC_ACQUIRE, __HIP_MEMORY_SCOPE_AGENT);
    }
    __syncthreads();

    const int b = bt0 >> 8;                 // T = 256
    const f4* Y4 = (const f4*)ws_Y + (size_t)b * 64 * 256;
    #pragma unroll
    for (int r = 0; r < 4; ++r) {
        const int bt = bt0 + r;
        f4 x = ((const f4*)ws_X)[(size_t)bt * 256 + tid];
        f4* O4 = (f4*)out + (size_t)bt * 64 * 256;
        #pragma unroll 4
        for (int u = 0; u < 64; ++u) {
            f4 y = Y4[u * 256 + tid];
            f4 v = { x.x + y.x, x.y + y.y, x.z + y.z, x.w + y.w };
            __builtin_nontemporal_store(v, &O4[u * 256 + tid]);
        }
    }
}

extern "C" void kernel_launch(void* const* d_in, const int* in_sizes, int n_in,
                              void* d_out, int out_size, void* d_ws, size_t ws_size,
                              hipStream_t stream) {
    (void)in_sizes; (void)n_in; (void)out_size; (void)ws_size;

    const int B = 8, T = 256, U = 64;
    const int ENC = 512, DEC = 640, J = 512, V = 1024;
    const int MT = B * T;   // 2048
    const int MU = B * U;   // 512

    const float* enc    = (const float*)d_in[0];
    const float* pred   = (const float*)d_in[1];
    const float* W_enc  = (const float*)d_in[2];
    const float* b_enc  = (const float*)d_in[3];
    const float* W_pred = (const float*)d_in[4];
    const float* b_pred = (const float*)d_in[5];
    const float* W_out  = (const float*)d_in[6];
    const float* b_out  = (const float*)d_in[7];
    float* out = (float*)d_out;

    const int n_Wo = V * 2 * J;   // 1048576
    const int n_e  = MT * J;      // 1048576
    const int n_p  = MU * J;      // 262144

    unsigned short* w = (unsigned short*)d_ws;
    unsigned short* Wo_h = w;                   // hi plane only
    unsigned short* e_h  = Wo_h + n_Wo;
    unsigned short* e_l  = e_h + n_e;
    unsigned short* p_h  = e_l + n_e;
    unsigned short* p_l  = p_h + n_p;
    float* ws_X = (float*)(p_l + n_p);          // (MT, V)
    float* ws_Y = ws_X + (size_t)MT * V;        // (MU, V)
    int*   flags = (int*)(ws_Y + (size_t)MU * V);

    zero_flags<<<1, 128, 0, stream>>>(flags, 34);

    // 1) merged e + p GEMMs (A split, W hi-only) + W_out hi-cvt blocks
    GJobF je = { enc,  W_enc,  ENC, ENC, b_enc,  e_h, e_l, J, ENC, MT / 64 };
    GJobF jp = { pred, W_pred, DEC, DEC, b_pred, p_h, p_l, J, DEC, MU / 64 };
    const int nbe = (MT / 64) * (J / 64);   // 256
    const int nbp = (MU / 64) * (J / 64);   // 64
    const int ncv = 64;
    gemmcvt64<<<nbe + nbp + ncv, 256, 0, stream>>>(
        je, jp, nbe, nbp, W_out, Wo_h, n_Wo / 8);

    // 2) fused {X,Y} GEMM + overlapped bcast (192 workers + 512 waiters)
    fused2<<<NG + 512, 256, 0, stream>>>(
        e_h, e_l, p_h, p_l, Wo_h, b_out, ws_X, ws_Y, out, flags);
}

// Round 15
// 130.392 us; speedup vs baseline: 1.3779x; 1.3779x over previous
//
#include <hip/hip_runtime.h>

typedef float f4 __attribute__((ext_vector_type(4)));
typedef float f32x4 __attribute__((ext_vector_type(4)));
typedef short bf16x8 __attribute__((ext_vector_type(8)));
typedef unsigned short u16x8 __attribute__((ext_vector_type(8)));

static __device__ __forceinline__ unsigned short f2bf(float f) {
    unsigned int x = __builtin_bit_cast(unsigned int, f);
    x = (x + 0x7fffu + ((x >> 16) & 1u)) >> 16;
    return (unsigned short)x;
}
static __device__ __forceinline__ float bf2f(unsigned short h) {
    unsigned int x = ((unsigned int)h) << 16;
    return __builtin_bit_cast(float, x);
}

static __device__ __forceinline__ void gll16(const unsigned short* g, unsigned short* l) {
    __builtin_amdgcn_global_load_lds(
        (__attribute__((address_space(1))) void*)(g),
        (__attribute__((address_space(3))) void*)(l), 16, 0, 0);
}

// LDS frag offset (shorts) for row r, true 16B-slot s (involution, both sides)
static __device__ __forceinline__ int fragoff(int r, int s) {
    return r * 32 + ((s ^ ((r >> 1) & 3)) << 3);
}

// XCD-chunked bijective swizzle (nblk % 8 == 0)
static __device__ __forceinline__ int xcd_swz(int raw, int nblk) {
    const int q = nblk >> 3;
    return (raw & 7) * q + (raw >> 3);
}

// ================= stage 1: merged {e,p} GEMM, A split hi+lo, W hi-only,
//                   in-staging f32->bf16 conversion + W_out cvt blocks.
//                   Output: bf16 hi plane only (stage-2 is pure bf16).
struct GJobF {
    const float *A, *W;
    int lda, ldw;
    const float* bias;
    unsigned short* Ch;
    int N, K, nbx;
};

__global__ __launch_bounds__(256, 3) void gemmcvt64(
    GJobF j0, GJobF j1, int nblk0, int nblk1,
    const float* __restrict__ Wo, unsigned short* __restrict__ Wo_h, int nWo8)
{
    __shared__ unsigned short lds[2][3][64 * 32];   // 2 bufs x {Ah,Al,Wh}

    const int bid = blockIdx.x;
    const int tid = threadIdx.x;

    if (bid >= nblk0 + nblk1) {
        const int nblkc = (int)gridDim.x - nblk0 - nblk1;
        for (int g = (bid - nblk0 - nblk1) * 256 + tid; g < nWo8; g += nblkc * 256) {
            const int idx = g * 8;
            f4 a = *(const f4*)(Wo + idx);
            f4 b = *(const f4*)(Wo + idx + 4);
            u16x8 hv;
            float s[8] = { a.x, a.y, a.z, a.w, b.x, b.y, b.z, b.w };
            #pragma unroll
            for (int i = 0; i < 8; ++i) hv[i] = f2bf(s[i]);
            *(u16x8*)(Wo_h + idx) = hv;
        }
        return;
    }

    const bool first = bid < nblk0;
    const GJobF J = first ? j0 : j1;
    const int raw = first ? bid : bid - nblk0;
    const int local = xcd_swz(raw, first ? nblk0 : nblk1);
    const int m0 = (local % J.nbx) * 64;
    const int n0 = (local / J.nbx) * 64;

    const int lane = tid & 63;
    const int wid  = tid >> 6;
    const int wr   = wid >> 1, wc = wid & 1;
    const int lrow = lane & 15;
    const int s    = lane >> 4;

    const int row  = tid >> 2, slot = tid & 3;
    const int woff = fragoff(row, slot);
    const float* pA = J.A + (size_t)(m0 + row) * J.lda + slot * 8;
    const float* pW = J.W + (size_t)(n0 + row) * J.ldw + slot * 8;

    f4 ra0, ra1, rw0, rw1;

#define LOADREGS(k0) do { \
    ra0 = *(const f4*)(pA + (k0));     ra1 = *(const f4*)(pA + (k0) + 4); \
    rw0 = *(const f4*)(pW + (k0));     rw1 = *(const f4*)(pW + (k0) + 4); \
} while (0)

#define CVTWRITE(buf) do { \
    u16x8 ha, la, hw; \
    float sa[8] = { ra0.x, ra0.y, ra0.z, ra0.w, ra1.x, ra1.y, ra1.z, ra1.w }; \
    float sw[8] = { rw0.x, rw0.y, rw0.z, rw0.w, rw1.x, rw1.y, rw1.z, rw1.w }; \
    _Pragma("unroll") \
    for (int i = 0; i < 8; ++i) { \
        unsigned short h = f2bf(sa[i]); \
        ha[i] = h; la[i] = f2bf(sa[i] - bf2f(h)); \
        hw[i] = f2bf(sw[i]); \
    } \
    *(u16x8*)&lds[buf][0][woff] = ha; \
    *(u16x8*)&lds[buf][1][woff] = la; \
    *(u16x8*)&lds[buf][2][woff] = hw; \
} while (0)

    f32x4 acc[2][2];
    #pragma unroll
    for (int i = 0; i < 2; ++i)
        #pragma unroll
        for (int j = 0; j < 2; ++j) acc[i][j] = (f32x4){0.f, 0.f, 0.f, 0.f};

    const int nt = J.K / 32;

    LOADREGS(0);
    CVTWRITE(0);
    __syncthreads();

    int cur = 0;
    for (int t = 0; t < nt; ++t) {
        if (t + 1 < nt) LOADREGS((t + 1) * 32);

        bf16x8 ah[2], al[2], wh[2];
        #pragma unroll
        for (int i = 0; i < 2; ++i) {
            const int ra = wr * 32 + i * 16 + lrow;
            const int rw = wc * 32 + i * 16 + lrow;
            ah[i] = *(const bf16x8*)&lds[cur][0][fragoff(ra, s)];
            al[i] = *(const bf16x8*)&lds[cur][1][fragoff(ra, s)];
            wh[i] = *(const bf16x8*)&lds[cur][2][fragoff(rw, s)];
        }
        #pragma unroll
        for (int i = 0; i < 2; ++i)
            #pragma unroll
            for (int j = 0; j < 2; ++j) {
                acc[i][j] = __builtin_amdgcn_mfma_f32_16x16x32_bf16(ah[i], wh[j], acc[i][j], 0, 0, 0);
                acc[i][j] = __builtin_amdgcn_mfma_f32_16x16x32_bf16(al[i], wh[j], acc[i][j], 0, 0, 0);
            }

        if (t + 1 < nt) {
            CVTWRITE(cur ^ 1);
            __syncthreads();
            cur ^= 1;
        }
    }
#undef LOADREGS
#undef CVTWRITE

    // epilogue: bf16 hi plane out; C/D layout col=lane&15, row=(lane>>4)*4+r
    #pragma unroll
    for (int i = 0; i < 2; ++i) {
        const int rbase = m0 + wr * 32 + i * 16 + (lane >> 4) * 4;
        #pragma unroll
        for (int j = 0; j < 2; ++j) {
            const int col = n0 + wc * 32 + j * 16 + (lane & 15);
            const float bv = J.bias[col];
            #pragma unroll
            for (int r = 0; r < 4; ++r)
                J.Ch[(size_t)(rbase + r) * J.N + col] = f2bf(acc[i][j][r] + bv);
        }
    }
}

// ================= stage 2: merged {X,Y} pure-bf16 GEMM, 64M x 128N tile,
//                   2-buf DMA staging, XCD swizzle, f32 out.
struct GJob {
    const unsigned short *A, *W;
    int lda, ldw;
    const float* bias;
    float* Cf;
    int N, K, nbx;
};

__global__ __launch_bounds__(256, 4) void gemm64x128(GJob j0, GJob j1, int nblk0)
{
    // per buf: A 64x32 (@0) + W 128x32 (@2048) shorts = 12 KB; 2 bufs = 24 KB
    __shared__ unsigned short lds[2][6144];

    const bool first = (int)blockIdx.x < nblk0;
    const GJob J = first ? j0 : j1;
    const int raw  = first ? (int)blockIdx.x : (int)blockIdx.x - nblk0;
    const int nblk = first ? nblk0 : ((int)gridDim.x - nblk0);
    const int local = xcd_swz(raw, nblk);   // m-fastest: XCD shares W n-panel
    const int m0 = (local % J.nbx) * 64;
    const int n0 = (local / J.nbx) * 128;

    const int tid  = threadIdx.x;
    const int lane = tid & 63;
    const int wid  = tid >> 6;
    const int wr   = wid >> 1, wc = wid & 1;
    const int lrow = lane & 15;
    const int s    = lane >> 4;

    // DMA staging (3 per wave per step): A rows wid*16.., W rows wid*32..
    const int arow  = wid * 16 + (lane >> 2);
    const int aslot = (lane & 3) ^ ((arow >> 1) & 3);
    const size_t gA = (size_t)(m0 + arow) * J.lda + aslot * 8;
    const int wrow0 = wid * 32 + (lane >> 2);
    const int wrow1 = wrow0 + 16;
    const int wsl0  = (lane & 3) ^ ((wrow0 >> 1) & 3);
    const int wsl1  = (lane & 3) ^ ((wrow1 >> 1) & 3);
    const size_t gW0 = (size_t)(n0 + wrow0) * J.ldw + wsl0 * 8;
    const size_t gW1 = (size_t)(n0 + wrow1) * J.ldw + wsl1 * 8;

#define STAGE(buf, k0) do { \
    gll16(J.A + gA + (k0),  &lds[buf][wid * 512]); \
    gll16(J.W + gW0 + (k0), &lds[buf][2048 + wid * 1024]); \
    gll16(J.W + gW1 + (k0), &lds[buf][2048 + wid * 1024 + 512]); \
} while (0)

    f32x4 acc[2][4];
    #pragma unroll
    for (int i = 0; i < 2; ++i)
        #pragma unroll
        for (int j = 0; j < 4; ++j) acc[i][j] = (f32x4){0.f, 0.f, 0.f, 0.f};

    const int nt = J.K / 32;

    STAGE(0, 0);
    asm volatile("s_waitcnt vmcnt(0)" ::: "memory");
    __syncthreads();

    int cur = 0;
    for (int t = 0; t < nt; ++t) {
        if (t + 1 < nt) STAGE(cur ^ 1, (t + 1) * 32);

        bf16x8 av[2], wv[4];
        #pragma unroll
        for (int i = 0; i < 2; ++i) {
            const int ra = wr * 32 + i * 16 + lrow;
            av[i] = *(const bf16x8*)&lds[cur][fragoff(ra, s)];
        }
        #pragma unroll
        for (int j = 0; j < 4; ++j) {
            const int rw = wc * 64 + j * 16 + lrow;    // 0..127
            wv[j] = *(const bf16x8*)&lds[cur][2048 + fragoff(rw, s)];
        }
        #pragma unroll
        for (int i = 0; i < 2; ++i)
            #pragma unroll
            for (int j = 0; j < 4; ++j)
                acc[i][j] = __builtin_amdgcn_mfma_f32_16x16x32_bf16(av[i], wv[j], acc[i][j], 0, 0, 0);

        if (t + 1 < nt) {
            asm volatile("s_waitcnt vmcnt(0)" ::: "memory");
            __syncthreads();
            cur ^= 1;
        }
    }
#undef STAGE

    #pragma unroll
    for (int i = 0; i < 2; ++i) {
        const int rbase = m0 + wr * 32 + i * 16 + (lane >> 4) * 4;
        #pragma unroll
        for (int j = 0; j < 4; ++j) {
            const int col = n0 + wc * 64 + j * 16 + (lane & 15);
            const float bv = J.bias ? J.bias[col] : 0.f;
            #pragma unroll
            for (int r = 0; r < 4; ++r)
                J.Cf[(size_t)(rbase + r) * J.N + col] = acc[i][j][r] + bv;
        }
    }
}

// ================= stage 3: out[(b,t),u,:] = X[(b,t),:] + Y[(b,u),:]
__global__ __launch_bounds__(256) void bcast_kernel(
    const float* __restrict__ X, const float* __restrict__ Y,
    float* __restrict__ out, int T, int U)
{
    const int Vq  = 256;           // 1024 / 4
    const int bt  = blockIdx.x;
    const int b   = bt / T;
    const int tid = threadIdx.x;

    const f4* X4 = (const f4*)X;
    const f4* Y4 = (const f4*)Y + (size_t)b * U * Vq;
    f4* O4 = (f4*)out + (size_t)bt * U * Vq;

    f4 x = X4[(size_t)bt * Vq + tid];
    #pragma unroll 4
    for (int u = 0; u < U; ++u) {
        f4 y = Y4[u * Vq + tid];
        f4 r = { x.x + y.x, x.y + y.y, x.z + y.z, x.w + y.w };
        __builtin_nontemporal_store(r, &O4[u * Vq + tid]);
    }
}

extern "C" void kernel_launch(void* const* d_in, const int* in_sizes, int n_in,
                              void* d_out, int out_size, void* d_ws, size_t ws_size,
                              hipStream_t stream) {
    (void)in_sizes; (void)n_in; (void)out_size; (void)ws_size;

    const int B = 8, T = 256, U = 64;
    const int ENC = 512, DEC = 640, J = 512, V = 1024;
    const int MT = B * T;   // 2048
    const int MU = B * U;   // 512

    const float* enc    = (const float*)d_in[0];
    const float* pred   = (const float*)d_in[1];
    const float* W_enc  = (const float*)d_in[2];
    const float* b_enc  = (const float*)d_in[3];
    const float* W_pred = (const float*)d_in[4];
    const float* b_pred = (const float*)d_in[5];
    const float* W_out  = (const float*)d_in[6];
    const float* b_out  = (const float*)d_in[7];
    float* out = (float*)d_out;

    const int n_Wo = V * 2 * J;   // 1048576
    const int n_e  = MT * J;      // 1048576
    const int n_p  = MU * J;      // 262144

    unsigned short* w = (unsigned short*)d_ws;
    unsigned short* Wo_h = w;                   // hi plane only
    unsigned short* e_h  = Wo_h + n_Wo;
    unsigned short* p_h  = e_h + n_e;
    float* ws_X = (float*)(p_h + n_p);          // (MT, V)
    float* ws_Y = ws_X + (size_t)MT * V;        // (MU, V)

    // 1) merged e + p GEMMs (A split, W hi-only; bf16 out) + W_out cvt blocks
    GJobF je = { enc,  W_enc,  ENC, ENC, b_enc,  e_h, J, ENC, MT / 64 };
    GJobF jp = { pred, W_pred, DEC, DEC, b_pred, p_h, J, DEC, MU / 64 };
    const int nbe = (MT / 64) * (J / 64);   // 256
    const int nbp = (MU / 64) * (J / 64);   // 64
    const int ncv = 64;
    gemmcvt64<<<nbe + nbp + ncv, 256, 0, stream>>>(
        je, jp, nbe, nbp, W_out, Wo_h, n_Wo / 8);

    // 2) merged X + Y pure-bf16 GEMMs, 64x128 tiles, XCD swizzle, f32 out
    GJob jx = { e_h, Wo_h,     J, 2 * J, b_out,   ws_X, V, J, MT / 64 };
    GJob jy = { p_h, Wo_h + J, J, 2 * J, nullptr, ws_Y, V, J, MU / 64 };
    const int nbx = (MT / 64) * (V / 128);   // 256
    const int nby = (MU / 64) * (V / 128);   // 64
    gemm64x128<<<nbx + nby, 256, 0, stream>>>(jx, jy, nbx);

    // 3) out = X broadcast + Y
    bcast_kernel<<<dim3(B * T), 256, 0, stream>>>(ws_X, ws_Y, out, T, U);
}

// Round 16
// 127.475 us; speedup vs baseline: 1.4095x; 1.0229x over previous
//
#include <hip/hip_runtime.h>

typedef float f4 __attribute__((ext_vector_type(4)));
typedef float f32x4 __attribute__((ext_vector_type(4)));
typedef short bf16x8 __attribute__((ext_vector_type(8)));
typedef unsigned short u16x8 __attribute__((ext_vector_type(8)));

static __device__ __forceinline__ unsigned short f2bf(float f) {
    unsigned int x = __builtin_bit_cast(unsigned int, f);
    x = (x + 0x7fffu + ((x >> 16) & 1u)) >> 16;
    return (unsigned short)x;
}

static __device__ __forceinline__ void gll16(const unsigned short* g, unsigned short* l) {
    __builtin_amdgcn_global_load_lds(
        (__attribute__((address_space(1))) void*)(g),
        (__attribute__((address_space(3))) void*)(l), 16, 0, 0);
}

// LDS frag offset (shorts) for row r, true 16B-slot s (involution, both sides)
static __device__ __forceinline__ int fragoff(int r, int s) {
    return r * 32 + ((s ^ ((r >> 1) & 3)) << 3);
}

// XCD-chunked bijective swizzle (nblk % 8 == 0)
static __device__ __forceinline__ int xcd_swz(int raw, int nblk) {
    const int q = nblk >> 3;
    return (raw & 7) * q + (raw >> 3);
}

// ================= stage 1: merged {e,p} pure-bf16 GEMM with in-staging
//                   f32->bf16 conversion + W_out cvt blocks. bf16 out.
struct GJobF {
    const float *A, *W;
    int lda, ldw;
    const float* bias;
    unsigned short* Ch;
    int N, K, nbx;
};

__global__ __launch_bounds__(256, 4) void gemmcvt64(
    GJobF j0, GJobF j1, int nblk0, int nblk1,
    const float* __restrict__ Wo, unsigned short* __restrict__ Wo_h, int nWo8)
{
    __shared__ unsigned short lds[2][2][64 * 32];   // 2 bufs x {A, W} = 16 KB

    const int bid = blockIdx.x;
    const int tid = threadIdx.x;

    if (bid >= nblk0 + nblk1) {
        const int nblkc = (int)gridDim.x - nblk0 - nblk1;
        for (int g = (bid - nblk0 - nblk1) * 256 + tid; g < nWo8; g += nblkc * 256) {
            const int idx = g * 8;
            f4 a = *(const f4*)(Wo + idx);
            f4 b = *(const f4*)(Wo + idx + 4);
            u16x8 hv;
            float s[8] = { a.x, a.y, a.z, a.w, b.x, b.y, b.z, b.w };
            #pragma unroll
            for (int i = 0; i < 8; ++i) hv[i] = f2bf(s[i]);
            *(u16x8*)(Wo_h + idx) = hv;
        }
        return;
    }

    const bool first = bid < nblk0;
    const GJobF J = first ? j0 : j1;
    const int raw = first ? bid : bid - nblk0;
    const int local = xcd_swz(raw, first ? nblk0 : nblk1);
    const int m0 = (local % J.nbx) * 64;
    const int n0 = (local / J.nbx) * 64;

    const int lane = tid & 63;
    const int wid  = tid >> 6;
    const int wr   = wid >> 1, wc = wid & 1;
    const int lrow = lane & 15;
    const int s    = lane >> 4;

    const int row  = tid >> 2, slot = tid & 3;
    const int woff = fragoff(row, slot);
    const float* pA = J.A + (size_t)(m0 + row) * J.lda + slot * 8;
    const float* pW = J.W + (size_t)(n0 + row) * J.ldw + slot * 8;

    f4 ra0, ra1, rw0, rw1;

#define LOADREGS(k0) do { \
    ra0 = *(const f4*)(pA + (k0));     ra1 = *(const f4*)(pA + (k0) + 4); \
    rw0 = *(const f4*)(pW + (k0));     rw1 = *(const f4*)(pW + (k0) + 4); \
} while (0)

#define CVTWRITE(buf) do { \
    u16x8 ha, hw; \
    float sa[8] = { ra0.x, ra0.y, ra0.z, ra0.w, ra1.x, ra1.y, ra1.z, ra1.w }; \
    float sw[8] = { rw0.x, rw0.y, rw0.z, rw0.w, rw1.x, rw1.y, rw1.z, rw1.w }; \
    _Pragma("unroll") \
    for (int i = 0; i < 8; ++i) { \
        ha[i] = f2bf(sa[i]); \
        hw[i] = f2bf(sw[i]); \
    } \
    *(u16x8*)&lds[buf][0][woff] = ha; \
    *(u16x8*)&lds[buf][1][woff] = hw; \
} while (0)

    f32x4 acc[2][2];
    #pragma unroll
    for (int i = 0; i < 2; ++i)
        #pragma unroll
        for (int j = 0; j < 2; ++j) acc[i][j] = (f32x4){0.f, 0.f, 0.f, 0.f};

    const int nt = J.K / 32;

    LOADREGS(0);
    CVTWRITE(0);
    __syncthreads();

    int cur = 0;
    for (int t = 0; t < nt; ++t) {
        if (t + 1 < nt) LOADREGS((t + 1) * 32);

        bf16x8 av[2], wv[2];
        #pragma unroll
        for (int i = 0; i < 2; ++i) {
            const int ra = wr * 32 + i * 16 + lrow;
            const int rw = wc * 32 + i * 16 + lrow;
            av[i] = *(const bf16x8*)&lds[cur][0][fragoff(ra, s)];
            wv[i] = *(const bf16x8*)&lds[cur][1][fragoff(rw, s)];
        }
        #pragma unroll
        for (int i = 0; i < 2; ++i)
            #pragma unroll
            for (int j = 0; j < 2; ++j)
                acc[i][j] = __builtin_amdgcn_mfma_f32_16x16x32_bf16(av[i], wv[j], acc[i][j], 0, 0, 0);

        if (t + 1 < nt) {
            CVTWRITE(cur ^ 1);
            __syncthreads();
            cur ^= 1;
        }
    }
#undef LOADREGS
#undef CVTWRITE

    // epilogue: bf16 out; C/D layout col=lane&15, row=(lane>>4)*4+r
    #pragma unroll
    for (int i = 0; i < 2; ++i) {
        const int rbase = m0 + wr * 32 + i * 16 + (lane >> 4) * 4;
        #pragma unroll
        for (int j = 0; j < 2; ++j) {
            const int col = n0 + wc * 32 + j * 16 + (lane & 15);
            const float bv = J.bias[col];
            #pragma unroll
            for (int r = 0; r < 4; ++r)
                J.Ch[(size_t)(rbase + r) * J.N + col] = f2bf(acc[i][j][r] + bv);
        }
    }
}

// ================= stage 2: merged {X,Y} pure-bf16 GEMM, 64M x 128N tile,
//                   2-buf DMA staging, XCD swizzle, f32 out.
struct GJob {
    const unsigned short *A, *W;
    int lda, ldw;
    const float* bias;
    float* Cf;
    int N, K, nbx;
};

__global__ __launch_bounds__(256, 4) void gemm64x128(GJob j0, GJob j1, int nblk0)
{
    // per buf: A 64x32 (@0) + W 128x32 (@2048) shorts = 12 KB; 2 bufs = 24 KB
    __shared__ unsigned short lds[2][6144];

    const bool first = (int)blockIdx.x < nblk0;
    const GJob J = first ? j0 : j1;
    const int raw  = first ? (int)blockIdx.x : (int)blockIdx.x - nblk0;
    const int nblk = first ? nblk0 : ((int)gridDim.x - nblk0);
    const int local = xcd_swz(raw, nblk);   // m-fastest: XCD shares W n-panel
    const int m0 = (local % J.nbx) * 64;
    const int n0 = (local / J.nbx) * 128;

    const int tid  = threadIdx.x;
    const int lane = tid & 63;
    const int wid  = tid >> 6;
    const int wr   = wid >> 1, wc = wid & 1;
    const int lrow = lane & 15;
    const int s    = lane >> 4;

    // DMA staging (3 per wave per step): A rows wid*16.., W rows wid*32..
    const int arow  = wid * 16 + (lane >> 2);
    const int aslot = (lane & 3) ^ ((arow >> 1) & 3);
    const size_t gA = (size_t)(m0 + arow) * J.lda + aslot * 8;
    const int wrow0 = wid * 32 + (lane >> 2);
    const int wrow1 = wrow0 + 16;
    const int wsl0  = (lane & 3) ^ ((wrow0 >> 1) & 3);
    const int wsl1  = (lane & 3) ^ ((wrow1 >> 1) & 3);
    const size_t gW0 = (size_t)(n0 + wrow0) * J.ldw + wsl0 * 8;
    const size_t gW1 = (size_t)(n0 + wrow1) * J.ldw + wsl1 * 8;

#define STAGE(buf, k0) do { \
    gll16(J.A + gA + (k0),  &lds[buf][wid * 512]); \
    gll16(J.W + gW0 + (k0), &lds[buf][2048 + wid * 1024]); \
    gll16(J.W + gW1 + (k0), &lds[buf][2048 + wid * 1024 + 512]); \
} while (0)

    f32x4 acc[2][4];
    #pragma unroll
    for (int i = 0; i < 2; ++i)
        #pragma unroll
        for (int j = 0; j < 4; ++j) acc[i][j] = (f32x4){0.f, 0.f, 0.f, 0.f};

    const int nt = J.K / 32;

    STAGE(0, 0);
    asm volatile("s_waitcnt vmcnt(0)" ::: "memory");
    __syncthreads();

    int cur = 0;
    for (int t = 0; t < nt; ++t) {
        if (t + 1 < nt) STAGE(cur ^ 1, (t + 1) * 32);

        bf16x8 av[2], wv[4];
        #pragma unroll
        for (int i = 0; i < 2; ++i) {
            const int ra = wr * 32 + i * 16 + lrow;
            av[i] = *(const bf16x8*)&lds[cur][fragoff(ra, s)];
        }
        #pragma unroll
        for (int j = 0; j < 4; ++j) {
            const int rw = wc * 64 + j * 16 + lrow;    // 0..127
            wv[j] = *(const bf16x8*)&lds[cur][2048 + fragoff(rw, s)];
        }
        #pragma unroll
        for (int i = 0; i < 2; ++i)
            #pragma unroll
            for (int j = 0; j < 4; ++j)
                acc[i][j] = __builtin_amdgcn_mfma_f32_16x16x32_bf16(av[i], wv[j], acc[i][j], 0, 0, 0);

        if (t + 1 < nt) {
            asm volatile("s_waitcnt vmcnt(0)" ::: "memory");
            __syncthreads();
            cur ^= 1;
        }
    }
#undef STAGE

    #pragma unroll
    for (int i = 0; i < 2; ++i) {
        const int rbase = m0 + wr * 32 + i * 16 + (lane >> 4) * 4;
        #pragma unroll
        for (int j = 0; j < 4; ++j) {
            const int col = n0 + wc * 64 + j * 16 + (lane & 15);
            const float bv = J.bias ? J.bias[col] : 0.f;
            #pragma unroll
            for (int r = 0; r < 4; ++r)
                J.Cf[(size_t)(rbase + r) * J.N + col] = acc[i][j][r] + bv;
        }
    }
}

// ================= stage 3: out[(b,t),u,:] = X[(b,t),:] + Y[(b,u),:]
__global__ __launch_bounds__(256) void bcast_kernel(
    const float* __restrict__ X, const float* __restrict__ Y,
    float* __restrict__ out, int T, int U)
{
    const int Vq  = 256;           // 1024 / 4
    const int bt  = blockIdx.x;
    const int b   = bt / T;
    const int tid = threadIdx.x;

    const f4* X4 = (const f4*)X;
    const f4* Y4 = (const f4*)Y + (size_t)b * U * Vq;
    f4* O4 = (f4*)out + (size_t)bt * U * Vq;

    f4 x = X4[(size_t)bt * Vq + tid];
    #pragma unroll 4
    for (int u = 0; u < U; ++u) {
        f4 y = Y4[u * Vq + tid];
        f4 r = { x.x + y.x, x.y + y.y, x.z + y.z, x.w + y.w };
        __builtin_nontemporal_store(r, &O4[u * Vq + tid]);
    }
}

extern "C" void kernel_launch(void* const* d_in, const int* in_sizes, int n_in,
                              void* d_out, int out_size, void* d_ws, size_t ws_size,
                              hipStream_t stream) {
    (void)in_sizes; (void)n_in; (void)out_size; (void)ws_size;

    const int B = 8, T = 256, U = 64;
    const int ENC = 512, DEC = 640, J = 512, V = 1024;
    const int MT = B * T;   // 2048
    const int MU = B * U;   // 512

    const float* enc    = (const float*)d_in[0];
    const float* pred   = (const float*)d_in[1];
    const float* W_enc  = (const float*)d_in[2];
    const float* b_enc  = (const float*)d_in[3];
    const float* W_pred = (const float*)d_in[4];
    const float* b_pred = (const float*)d_in[5];
    const float* W_out  = (const float*)d_in[6];
    const float* b_out  = (const float*)d_in[7];
    float* out = (float*)d_out;

    const int n_Wo = V * 2 * J;   // 1048576
    const int n_e  = MT * J;      // 1048576
    const int n_p  = MU * J;      // 262144

    unsigned short* w = (unsigned short*)d_ws;
    unsigned short* Wo_h = w;                   // hi plane only
    unsigned short* e_h  = Wo_h + n_Wo;
    unsigned short* p_h  = e_h + n_e;
    float* ws_X = (float*)(p_h + n_p);          // (MT, V)
    float* ws_Y = ws_X + (size_t)MT * V;        // (MU, V)

    // 1) merged e + p pure-bf16 GEMMs (in-staging cvt) + W_out cvt blocks
    GJobF je = { enc,  W_enc,  ENC, ENC, b_enc,  e_h, J, ENC, MT / 64 };
    GJobF jp = { pred, W_pred, DEC, DEC, b_pred, p_h, J, DEC, MU / 64 };
    const int nbe = (MT / 64) * (J / 64);   // 256
    const int nbp = (MU / 64) * (J / 64);   // 64
    const int ncv = 64;
    gemmcvt64<<<nbe + nbp + ncv, 256, 0, stream>>>(
        je, jp, nbe, nbp, W_out, Wo_h, n_Wo / 8);

    // 2) merged X + Y pure-bf16 GEMMs, 64x128 tiles, XCD swizzle, f32 out
    GJob jx = { e_h, Wo_h,     J, 2 * J, b_out,   ws_X, V, J, MT / 64 };
    GJob jy = { p_h, Wo_h + J, J, 2 * J, nullptr, ws_Y, V, J, MU / 64 };
    const int nbx = (MT / 64) * (V / 128);   // 256
    const int nby = (MU / 64) * (V / 128);   // 64
    gemm64x128<<<nbx + nby, 256, 0, stream>>>(jx, jy, nbx);

    // 3) out = X broadcast + Y
    bcast_kernel<<<dim3(B * T), 256, 0, stream>>>(ws_X, ws_Y, out, T, U);
}